// Round 3
// 208.765 us; speedup vs baseline: 1.0326x; 1.0326x over previous
//
#include <hip/hip_runtime.h>
#include <hip/hip_bf16.h>
#include <cstdint>

#define DIM   1024
#define HEADS 16
#define HDIM  64
#define BATCH 2
#define SEQ   2048
#define ROWS  (BATCH*SEQ)   // 4096
static constexpr float QSCALE = 0.18033688f;        // HDIM^-0.5 * log2(e)

typedef float  f32x4  __attribute__((ext_vector_type(4)));
typedef float  f32x16 __attribute__((ext_vector_type(16)));
typedef float  float4v __attribute__((ext_vector_type(4)));
typedef __bf16 bf16x8 __attribute__((ext_vector_type(8)));
typedef __bf16 bf16x4 __attribute__((ext_vector_type(4)));
typedef __bf16 bf16x2 __attribute__((ext_vector_type(2)));
typedef unsigned u32x4v __attribute__((ext_vector_type(4)));

// async global->LDS, 16B per lane; LDS dest is wave-uniform base + lane*16B
__device__ __forceinline__ void glds16(const __bf16* g, __bf16* l) {
  __builtin_amdgcn_global_load_lds(
      (const __attribute__((address_space(1))) void*)g,
      (__attribute__((address_space(3))) void*)l, 16, 0, 0);
}

// Explicit drain of async global->LDS DMAs. global_load_lds has NO consuming
// data dependence, so its completion is ordered only by vmcnt; this guard
// guarantees the drain happens before the following __syncthreads() even if
// the compiler's pre-barrier waitcnt tracking misses the builtin-issued DMAs.
__device__ __forceinline__ void wait_dma0() {
  asm volatile("s_waitcnt vmcnt(0) lgkmcnt(0)" ::: "memory");
}

// ---------------------------------------------------------------------------
// prep: z 0..7 -> fp32->bf16 convert of [x|y]; z == 8 -> W -> Wt[n][k] bf16.
// ---------------------------------------------------------------------------
__global__ __launch_bounds__(256) void prep_kernel(
    const float* __restrict__ x, const float* __restrict__ y,
    const float* __restrict__ Wq, const float* __restrict__ Wk,
    const float* __restrict__ Wv, const float* __restrict__ Wp,
    __bf16* __restrict__ xb, __bf16* __restrict__ yb, __bf16* __restrict__ Wt) {
  const int z = blockIdx.z, t = threadIdx.x;
  const size_t NEL = (size_t)ROWS * DIM;
  if (z < 8) {
    size_t idx = (((size_t)z * 1024 + blockIdx.x) * 256 + t) * 4;
    const float* s; __bf16* d;
    if (idx < NEL) { s = x + idx; d = xb + idx; }
    else           { s = y + (idx - NEL); d = yb + (idx - NEL); }
    const float4v v = *(const float4v*)s;
    bf16x4 o;
    o[0] = (__bf16)v[0]; o[1] = (__bf16)v[1]; o[2] = (__bf16)v[2]; o[3] = (__bf16)v[3];
    *(bf16x4*)d = o;
    return;
  }
  const int w = blockIdx.x >> 8, rem = blockIdx.x & 255;
  const float* W = (w == 0) ? Wq : (w == 1) ? Wk : (w == 2) ? Wv : Wp;
  __bf16* dst = Wt + (size_t)w * DIM * DIM;
  const int n0 = (rem & 15) * 64, k0 = (rem >> 4) * 64;
  __shared__ float T[64][65];
  const int col = t & 63, rw = t >> 6;
  #pragma unroll
  for (int p = 0; p < 16; ++p) {
    const int row = p * 4 + rw;
    T[row][col] = W[(size_t)(k0 + row) * DIM + n0 + col];
  }
  __syncthreads();
  #pragma unroll
  for (int p = 0; p < 16; ++p) {
    const int row = p * 4 + rw;
    dst[(size_t)(n0 + row) * DIM + k0 + col] = (__bf16)T[col][row];
  }
}

// ---------------------------------------------------------------------------
// Fused QKV projection, one 768-block dispatch (3 blocks/CU).
// z: 0 -> Q = xb@Wq^T * QSCALE, 1 -> K = yb@Wk^T, 2 -> V = yb@Wv^T written
// TRANSPOSED to VT[(b*16+h)*64+d][key] via swizzled in-LDS transpose.
// ---------------------------------------------------------------------------
__global__ __launch_bounds__(256) void proj_kernel(
    const __bf16* __restrict__ xb, const __bf16* __restrict__ yb,
    const __bf16* __restrict__ Wt,
    __bf16* __restrict__ Qb, __bf16* __restrict__ Kb, __bf16* __restrict__ VT) {
  const int z = blockIdx.z;
  const __bf16* A = (z == 0) ? xb : yb;
  const __bf16* Bt = Wt + (size_t)z * DIM * DIM;

  __shared__ __bf16 S[2][128 * 64];   // staging; S[0..1] reused for transpose
  __bf16* As = S[0];
  __bf16* Bs = S[1];

  const int t = threadIdx.x, lane = t & 63, wave = t >> 6;
  const int l15 = lane & 15, quad = lane >> 4;
  const int wm = wave & 1, wn = wave >> 1;
  const int rowBase = blockIdx.y * 128, colBase = blockIdx.x * 128;
  const int srow = lane >> 3;
  const int scol = ((lane & 7) ^ srow) * 8;

  f32x4 acc[4][4] = {};

  for (int kb = 0; kb < DIM; kb += 64) {
    __syncthreads();
    #pragma unroll
    for (int i = 0; i < 4; ++i) {
      const int c = wave * 4 + i;
      const int row = c * 8 + srow;
      glds16(&A[(size_t)(rowBase + row) * DIM + kb + scol], &As[c * 512]);
      glds16(&Bt[(size_t)(colBase + row) * DIM + kb + scol], &Bs[c * 512]);
    }
    __syncthreads();
    #pragma unroll
    for (int ks = 0; ks < 2; ++ks) {
      bf16x8 a[4], b[4];
      #pragma unroll
      for (int mi = 0; mi < 4; ++mi) {
        const int row = wm * 64 + mi * 16 + l15;
        a[mi] = *(const bf16x8*)&As[row * 64 + (((ks << 2) | quad) ^ (row & 7)) * 8];
      }
      #pragma unroll
      for (int ni = 0; ni < 4; ++ni) {
        const int row = wn * 64 + ni * 16 + l15;
        b[ni] = *(const bf16x8*)&Bs[row * 64 + (((ks << 2) | quad) ^ (row & 7)) * 8];
      }
      #pragma unroll
      for (int mi = 0; mi < 4; ++mi)
        #pragma unroll
        for (int ni = 0; ni < 4; ++ni)
          acc[mi][ni] = __builtin_amdgcn_mfma_f32_16x16x32_bf16(a[mi], b[ni], acc[mi][ni], 0, 0, 0);
    }
  }

  if (z < 2) {
    __bf16* out = (z == 0) ? Qb : Kb;
    const float sc = (z == 0) ? QSCALE : 1.0f;
    #pragma unroll
    for (int mi = 0; mi < 4; ++mi) {
      const int row0 = rowBase + wm * 64 + mi * 16 + quad * 4;
      #pragma unroll
      for (int ni = 0; ni < 4; ++ni) {
        const int col = colBase + wn * 64 + ni * 16 + l15;
        #pragma unroll
        for (int r = 0; r < 4; ++r)
          out[(size_t)(row0 + r) * DIM + col] = (__bf16)(acc[mi][ni][r] * sc);
      }
    }
    return;
  }

  // z == 2: transpose epilogue (verified R8). Ts element (d,k) at
  // d*128 + ((k>>3)^(d&7))*8 + (k&7); rows=keys, cols=d.
  __syncthreads();
  __bf16* Ts = &S[0][0];              // 128x128 bf16 = 32 KB
  #pragma unroll
  for (int mi = 0; mi < 4; ++mi) {
    const int bk3 = wm * 8 + mi * 2 + (quad >> 1);   // key_local >> 3
    #pragma unroll
    for (int ni = 0; ni < 4; ++ni) {
      const int dl = wn * 64 + ni * 16 + l15;        // d_local
      bf16x4 pk;
      #pragma unroll
      for (int r = 0; r < 4; ++r) pk[r] = (__bf16)acc[mi][ni][r];
      *(bf16x4*)&Ts[dl * 128 + (bk3 ^ (dl & 7)) * 8 + (quad & 1) * 4] = pk;
    }
  }
  __syncthreads();
  const int d = t >> 1, khh = t & 1;
  const size_t vrow = (size_t)((rowBase >> 11) * HEADS * HDIM) + colBase + d;
  const int key0g = rowBase & (SEQ - 1);
  #pragma unroll
  for (int j = 0; j < 8; ++j) {
    const int kc = khh * 8 + j;
    const int lc = (kc & 8) | ((kc ^ d) & 7);
    const bf16x8 v = *(const bf16x8*)&Ts[d * 128 + lc * 8];
    *(bf16x8*)&VT[vrow * SEQ + key0g + kc * 8] = v;
  }
}

// ---------------------------------------------------------------------------
// Flash attention v7c: full-rate 32x32x16 MFMA everywhere.
// Block = 4 waves, each wave owns 32 q-rows x ALL keys (no kh split, no
// cross-wave merge). Swapped QK^T (mfma(K,Q)) puts P row=key, col=q; P is
// packed to bf16 and redistributed with permlane32_swap into the A-frags of
// full-rate 32x32x16 PV MFMAs (T12). Row sums on the VALU accumulate the
// BF16-ROUNDED p (recovered from the packed word) so numerator and
// denominator share rounding (v6-proven semantics). Double-buffered K/V
// staging; EXPLICIT vmcnt(0) drain before the barrier closes the
// global_load_lds visibility race (v7/v7b intermittent divergence).
// ---------------------------------------------------------------------------
__global__ __launch_bounds__(256, 2) void attn_kernel(
    const __bf16* __restrict__ Qb, const __bf16* __restrict__ Kb,
    const __bf16* __restrict__ VT, __bf16* __restrict__ Ob) {
  __shared__ __bf16 KV[2][2][64 * 64];   // [buf][K|V][64x64], XOR-swizzled rows

  const int t = threadIdx.x, lane = t & 63, wave = t >> 6;
  const int x = lane & 31, hi = lane >> 5;
  const int bh = blockIdx.y, b = bh >> 4, h = bh & 15;
  const int qbase = blockIdx.x * 128 + wave * 32;
  const int srow = lane >> 3;
  const int scol = ((lane & 7) ^ srow) * 8;

  const __bf16* Kbh = Kb + (size_t)b * SEQ * DIM + h * HDIM;
  const __bf16* Vbh = VT + (size_t)bh * HDIM * SEQ;

  // Q B-frags: col = x = q_local, k = kd*16 + hi*8 + j  (Q pre-scaled by QSCALE)
  bf16x8 qf[4];
  #pragma unroll
  for (int kd = 0; kd < 4; ++kd)
    qf[kd] = *(const bf16x8*)&Qb[(size_t)(b * SEQ + qbase + x) * DIM
                                 + h * HDIM + kd * 16 + hi * 8];

  f32x16 o0 = {}, o1 = {};   // o[dblock]: row=q=crow(r,hi), col=d=dblock*32+x
  float lsum = 0.f;          // per-lane partial rowsum for q=x (own hi-half keys)

  const int he16 = (hi ^ (x & 7)) << 4;  // swizzle slot byte base
  const int rowb = x * 128;              // LDS row byte offset (key row / d row)

  auto stage = [&](int jb, int buf) {
    #pragma unroll
    for (int i = 0; i < 2; ++i) {
      const int c = wave * 2 + i;
      const int row = c * 8 + srow;
      glds16(&Kbh[(size_t)(jb + row) * DIM + scol], &KV[buf][0][c * 512]);
      glds16(&Vbh[(size_t)row * SEQ + jb + scol], &KV[buf][1][c * 512]);
    }
  };

  stage(0, 0);
  for (int j = 0; j < SEQ / 64; ++j) {
    const int buf = j & 1;
    wait_dma0();               // guarantee this wave's DMAs landed in LDS
    __syncthreads();           // ...before any wave reads the staged tile
    if (j + 1 < SEQ / 64) stage((j + 1) * 64, buf ^ 1);
    const char* Ks = (const char*)KV[buf][0];
    const char* Vs = (const char*)KV[buf][1];

    // QK^T, both 32-key subtiles: sT col=q(x), row=key=crow(r,hi)
    f32x16 sT0 = {}, sT1 = {};
    #pragma unroll
    for (int kd = 0; kd < 4; ++kd) {
      const bf16x8 kf = *(const bf16x8*)(Ks + rowb + (he16 ^ (kd << 5)));
      sT0 = __builtin_amdgcn_mfma_f32_32x32x16_bf16(kf, qf[kd], sT0, 0, 0, 0);
    }
    #pragma unroll
    for (int kd = 0; kd < 4; ++kd) {
      const bf16x8 kf = *(const bf16x8*)(Ks + 4096 + rowb + (he16 ^ (kd << 5)));
      sT1 = __builtin_amdgcn_mfma_f32_32x32x16_bf16(kf, qf[kd], sT1, 0, 0, 0);
    }

    // per subtile: exp2 -> pack -> permlane swap -> PV (kt=1 pack overlaps kt=0 PV)
    #pragma unroll
    for (int kt = 0; kt < 2; ++kt) {
      const f32x16 s = kt ? sT1 : sT0;
      unsigned w[8];
      #pragma unroll
      for (int i = 0; i < 8; ++i) {
        const float p0 = __builtin_amdgcn_exp2f(s[2 * i]);
        const float p1 = __builtin_amdgcn_exp2f(s[2 * i + 1]);
        bf16x2 pk; pk[0] = (__bf16)p0; pk[1] = (__bf16)p1;
        const unsigned u = __builtin_bit_cast(unsigned, pk);
        w[i] = u;
        // denominator sums the BF16-ROUNDED p (matches the PV numerator's
        // rounding; bf16->f32 is just a shift / mask on the packed word)
        lsum += __builtin_bit_cast(float, u << 16)
              + __builtin_bit_cast(float, u & 0xffff0000u);
      }
      // F0 = keys [kt*32, kt*32+16): dwords {w0,w1,partner w0,w1} per hi-half
      // F1 = keys [kt*32+16, kt*32+32)
#if __has_builtin(__builtin_amdgcn_permlane32_swap)
      const auto s02 = __builtin_amdgcn_permlane32_swap(w[0], w[2], false, false);
      const auto s13 = __builtin_amdgcn_permlane32_swap(w[1], w[3], false, false);
      const auto s46 = __builtin_amdgcn_permlane32_swap(w[4], w[6], false, false);
      const auto s57 = __builtin_amdgcn_permlane32_swap(w[5], w[7], false, false);
      const u32x4v f0v = {(unsigned)s02[0], (unsigned)s13[0], (unsigned)s02[1], (unsigned)s13[1]};
      const u32x4v f1v = {(unsigned)s46[0], (unsigned)s57[0], (unsigned)s46[1], (unsigned)s57[1]};
#else
      const unsigned q0 = __shfl_xor((int)w[0], 32, 64), q1 = __shfl_xor((int)w[1], 32, 64);
      const unsigned q2 = __shfl_xor((int)w[2], 32, 64), q3 = __shfl_xor((int)w[3], 32, 64);
      const unsigned q4 = __shfl_xor((int)w[4], 32, 64), q5 = __shfl_xor((int)w[5], 32, 64);
      const unsigned q6 = __shfl_xor((int)w[6], 32, 64), q7 = __shfl_xor((int)w[7], 32, 64);
      const u32x4v f0v = {hi ? q2 : w[0], hi ? q3 : w[1], hi ? w[2] : q0, hi ? w[3] : q1};
      const u32x4v f1v = {hi ? q6 : w[4], hi ? q7 : w[5], hi ? w[6] : q4, hi ? w[7] : q5};
#endif
      const bf16x8 F0 = __builtin_bit_cast(bf16x8, f0v);
      const bf16x8 F1 = __builtin_bit_cast(bf16x8, f1v);

      // PV: V B-frag col=d (=dblock*32+x), k=hi*8+j keys; slot group
      // (kt*4 + kfr*2 + hi) ^ (d&7) -> byte he16 ^ (kt<<6) ^ (kfr<<5)
      const int kb0 = kt << 6;
      {
        const bf16x8 va = *(const bf16x8*)(Vs + rowb + (he16 ^ kb0));
        const bf16x8 vb = *(const bf16x8*)(Vs + 4096 + rowb + (he16 ^ kb0));
        o0 = __builtin_amdgcn_mfma_f32_32x32x16_bf16(F0, va, o0, 0, 0, 0);
        o1 = __builtin_amdgcn_mfma_f32_32x32x16_bf16(F0, vb, o1, 0, 0, 0);
      }
      {
        const bf16x8 va = *(const bf16x8*)(Vs + rowb + (he16 ^ (kb0 | 32)));
        const bf16x8 vb = *(const bf16x8*)(Vs + 4096 + rowb + (he16 ^ (kb0 | 32)));
        o0 = __builtin_amdgcn_mfma_f32_32x32x16_bf16(F1, va, o0, 0, 0, 0);
        o1 = __builtin_amdgcn_mfma_f32_32x32x16_bf16(F1, vb, o1, 0, 0, 0);
      }
    }
  }

  // finish: l[q=x] = own-half sum + partner-half sum; normalize + write.
  const float ltot = lsum + __shfl_xor(lsum, 32, 64);
  const float linv = 1.f / ltot;
  #pragma unroll
  for (int r = 0; r < 16; ++r) {
    const int q = (r & 3) + 8 * (r >> 2) + 4 * hi;
    const float inv = __shfl(linv, q, 64);   // linv lives at lane q (both halves)
    __bf16* dst = &Ob[(size_t)(b * SEQ + qbase + q) * DIM + h * HDIM + x];
    dst[0]  = (__bf16)(o0[r] * inv);
    dst[32] = (__bf16)(o1[r] * inv);
  }
}

// ---------------------------------------------------------------------------
// Output projection: 64x128 tile (512 blocks = 2/CU), fp32 out + bias.
// ---------------------------------------------------------------------------
__global__ __launch_bounds__(256) void outproj_kernel(
    const __bf16* __restrict__ A, const __bf16* __restrict__ Bt,
    const float* __restrict__ bias, float* __restrict__ out) {
  __shared__ __bf16 As[64 * 64];
  __shared__ __bf16 Bs[128 * 64];

  const int t = threadIdx.x, lane = t & 63, wave = t >> 6;
  const int l15 = lane & 15, quad = lane >> 4;
  const int wm = wave & 1, wn = wave >> 1;
  const int rowBase = blockIdx.y * 64, colBase = blockIdx.x * 128;
  const int srow = lane >> 3;
  const int scol = ((lane & 7) ^ srow) * 8;

  f32x4 acc[2][4] = {};

  for (int kb = 0; kb < DIM; kb += 64) {
    __syncthreads();
    #pragma unroll
    for (int i = 0; i < 2; ++i) {
      const int c = wave * 2 + i;
      const int row = c * 8 + srow;
      glds16(&A[(size_t)(rowBase + row) * DIM + kb + scol], &As[c * 512]);
    }
    #pragma unroll
    for (int i = 0; i < 4; ++i) {
      const int c = wave * 4 + i;
      const int row = c * 8 + srow;
      glds16(&Bt[(size_t)(colBase + row) * DIM + kb + scol], &Bs[c * 512]);
    }
    __syncthreads();
    #pragma unroll
    for (int ks = 0; ks < 2; ++ks) {
      bf16x8 a[2], b[4];
      #pragma unroll
      for (int mi = 0; mi < 2; ++mi) {
        const int row = wm * 32 + mi * 16 + l15;
        a[mi] = *(const bf16x8*)&As[row * 64 + (((ks << 2) | quad) ^ (row & 7)) * 8];
      }
      #pragma unroll
      for (int ni = 0; ni < 4; ++ni) {
        const int row = wn * 64 + ni * 16 + l15;
        b[ni] = *(const bf16x8*)&Bs[row * 64 + (((ks << 2) | quad) ^ (row & 7)) * 8];
      }
      #pragma unroll
      for (int mi = 0; mi < 2; ++mi)
        #pragma unroll
        for (int ni = 0; ni < 4; ++ni)
          acc[mi][ni] = __builtin_amdgcn_mfma_f32_16x16x32_bf16(a[mi], b[ni], acc[mi][ni], 0, 0, 0);
    }
  }

  #pragma unroll
  for (int mi = 0; mi < 2; ++mi) {
    const int row0 = rowBase + wm * 32 + mi * 16 + quad * 4;
    #pragma unroll
    for (int ni = 0; ni < 4; ++ni) {
      const int col = colBase + wn * 64 + ni * 16 + l15;
      const float bb = bias[col];
      #pragma unroll
      for (int r = 0; r < 4; ++r)
        out[(size_t)(row0 + r) * DIM + col] = acc[mi][ni][r] + bb;
    }
  }
}

// ---------------------------------------------------------------------------
// ws layout (bf16, NEL = 4194304): xb yb Wt[4M] Qb Kb VT = 50.3 MB.
// Ob aliases xb (dead after projections).
// ---------------------------------------------------------------------------
extern "C" void kernel_launch(void* const* d_in, const int* in_sizes, int n_in,
                              void* d_out, int out_size, void* d_ws, size_t ws_size,
                              hipStream_t stream) {
  const float* x  = (const float*)d_in[0];
  const float* y  = (const float*)d_in[1];
  const float* Wq = (const float*)d_in[2];
  const float* Wk = (const float*)d_in[3];
  const float* Wv = (const float*)d_in[4];
  const float* Wp = (const float*)d_in[5];
  const float* bp = (const float*)d_in[6];
  float* out = (float*)d_out;

  const size_t NEL = (size_t)ROWS * DIM;
  __bf16* xb = (__bf16*)d_ws;
  __bf16* yb = xb + NEL;
  __bf16* Wt = yb + NEL;            // [4][1024][1024] (q,k,v,p), transposed [n][k]
  __bf16* Qb = Wt + NEL;
  __bf16* Kb = Qb + NEL;
  __bf16* VT = Kb + NEL;
  __bf16* Ob = xb;                  // alias: xb dead after projections

  prep_kernel<<<dim3(1024, 1, 9), 256, 0, stream>>>(x, y, Wq, Wk, Wv, Wp, xb, yb, Wt);
  proj_kernel<<<dim3(DIM / 128, ROWS / 128, 3), 256, 0, stream>>>(xb, yb, Wt, Qb, Kb, VT);
  attn_kernel<<<dim3(SEQ / 128, BATCH * HEADS), 256, 0, stream>>>(Qb, Kb, VT, Ob);
  outproj_kernel<<<dim3(DIM / 128, ROWS / 64), 256, 0, stream>>>(Ob, Wt + 3 * NEL / 4, bp, out);
}

// Round 4
// 187.378 us; speedup vs baseline: 1.1504x; 1.1141x over previous
//
#include <hip/hip_runtime.h>
#include <hip/hip_bf16.h>
#include <cstdint>

#define DIM   1024
#define HEADS 16
#define HDIM  64
#define BATCH 2
#define SEQ   2048
#define ROWS  (BATCH*SEQ)   // 4096
static constexpr float QSCALE = 0.18033688f;        // HDIM^-0.5 * log2(e)

typedef float  f32x4  __attribute__((ext_vector_type(4)));
typedef float  f32x16 __attribute__((ext_vector_type(16)));
typedef float  float4v __attribute__((ext_vector_type(4)));
typedef __bf16 bf16x8 __attribute__((ext_vector_type(8)));
typedef __bf16 bf16x4 __attribute__((ext_vector_type(4)));
typedef __bf16 bf16x2 __attribute__((ext_vector_type(2)));
typedef unsigned u32x4v __attribute__((ext_vector_type(4)));

// async global->LDS, 16B per lane; LDS dest is wave-uniform base + lane*16B
__device__ __forceinline__ void glds16(const __bf16* g, __bf16* l) {
  __builtin_amdgcn_global_load_lds(
      (const __attribute__((address_space(1))) void*)g,
      (__attribute__((address_space(3))) void*)l, 16, 0, 0);
}

// Explicit drain of async global->LDS DMAs before publishing via barrier.
__device__ __forceinline__ void wait_dma0() {
  asm volatile("s_waitcnt vmcnt(0) lgkmcnt(0)" ::: "memory");
}

// ---------------------------------------------------------------------------
// prep: z 0..7 -> fp32->bf16 convert of [x|y]; z == 8 -> W -> Wt[n][k] bf16.
// ---------------------------------------------------------------------------
__global__ __launch_bounds__(256) void prep_kernel(
    const float* __restrict__ x, const float* __restrict__ y,
    const float* __restrict__ Wq, const float* __restrict__ Wk,
    const float* __restrict__ Wv, const float* __restrict__ Wp,
    __bf16* __restrict__ xb, __bf16* __restrict__ yb, __bf16* __restrict__ Wt) {
  const int z = blockIdx.z, t = threadIdx.x;
  const size_t NEL = (size_t)ROWS * DIM;
  if (z < 8) {
    size_t idx = (((size_t)z * 1024 + blockIdx.x) * 256 + t) * 4;
    const float* s; __bf16* d;
    if (idx < NEL) { s = x + idx; d = xb + idx; }
    else           { s = y + (idx - NEL); d = yb + (idx - NEL); }
    const float4v v = *(const float4v*)s;
    bf16x4 o;
    o[0] = (__bf16)v[0]; o[1] = (__bf16)v[1]; o[2] = (__bf16)v[2]; o[3] = (__bf16)v[3];
    *(bf16x4*)d = o;
    return;
  }
  const int w = blockIdx.x >> 8, rem = blockIdx.x & 255;
  const float* W = (w == 0) ? Wq : (w == 1) ? Wk : (w == 2) ? Wv : Wp;
  __bf16* dst = Wt + (size_t)w * DIM * DIM;
  const int n0 = (rem & 15) * 64, k0 = (rem >> 4) * 64;
  __shared__ float T[64][65];
  const int col = t & 63, rw = t >> 6;
  #pragma unroll
  for (int p = 0; p < 16; ++p) {
    const int row = p * 4 + rw;
    T[row][col] = W[(size_t)(k0 + row) * DIM + n0 + col];
  }
  __syncthreads();
  #pragma unroll
  for (int p = 0; p < 16; ++p) {
    const int row = p * 4 + rw;
    dst[(size_t)(n0 + row) * DIM + k0 + col] = (__bf16)T[col][row];
  }
}

// ---------------------------------------------------------------------------
// Fused QKV projection v2: double-buffered stage-ahead K-loop (one barrier
// per K-step, DMAs for tile j+1 in flight during compute of tile j) + XCD-
// aware bijective block swizzle (768 = 8 x 96) so blocks sharing an A panel
// share one XCD's L2.
// z: 0 -> Q = xb@Wq^T * QSCALE, 1 -> K = yb@Wk^T, 2 -> V = yb@Wv^T written
// TRANSPOSED to VT[(b*16+h)*64+d][key] via swizzled in-LDS transpose.
// ---------------------------------------------------------------------------
__global__ __launch_bounds__(256, 2) void proj_kernel(
    const __bf16* __restrict__ xb, const __bf16* __restrict__ yb,
    const __bf16* __restrict__ Wt,
    __bf16* __restrict__ Qb, __bf16* __restrict__ Kb, __bf16* __restrict__ VT) {
  // bijective XCD swizzle: linear id in dispatch order (x fastest) -> role id
  const int lin = blockIdx.x + 8 * (blockIdx.y + 32 * blockIdx.z);
  const int swz = (lin & 7) * 96 + (lin >> 3);       // 96 roles per XCD
  const int bx = swz & 7, by = (swz >> 3) & 31, z = swz >> 8;

  const __bf16* A = (z == 0) ? xb : yb;
  const __bf16* Bt = Wt + (size_t)z * DIM * DIM;

  __shared__ __bf16 S[2][2][128 * 64];   // [buf][A|B]; 64 KB

  const int t = threadIdx.x, lane = t & 63, wave = t >> 6;
  const int l15 = lane & 15, quad = lane >> 4;
  const int wm = wave & 1, wn = wave >> 1;
  const int rowBase = by * 128, colBase = bx * 128;
  const int srow = lane >> 3;
  const int scol = ((lane & 7) ^ srow) * 8;

  f32x4 acc[4][4] = {};

  auto stage = [&](int kb, int buf) {
    #pragma unroll
    for (int i = 0; i < 4; ++i) {
      const int c = wave * 4 + i;
      const int row = c * 8 + srow;
      glds16(&A[(size_t)(rowBase + row) * DIM + kb + scol], &S[buf][0][c * 512]);
      glds16(&Bt[(size_t)(colBase + row) * DIM + kb + scol], &S[buf][1][c * 512]);
    }
  };

  stage(0, 0);
  for (int j = 0; j < DIM / 64; ++j) {
    const int buf = j & 1;
    wait_dma0();               // stage(j) landed (compute of j-1 covered it)
    __syncthreads();           // publish buf; all waves done with buf^1
    if (j + 1 < DIM / 64) stage((j + 1) * 64, buf ^ 1);
    const __bf16* As = S[buf][0];
    const __bf16* Bs = S[buf][1];
    #pragma unroll
    for (int ks = 0; ks < 2; ++ks) {
      bf16x8 a[4], b[4];
      #pragma unroll
      for (int mi = 0; mi < 4; ++mi) {
        const int row = wm * 64 + mi * 16 + l15;
        a[mi] = *(const bf16x8*)&As[row * 64 + (((ks << 2) | quad) ^ (row & 7)) * 8];
      }
      #pragma unroll
      for (int ni = 0; ni < 4; ++ni) {
        const int row = wn * 64 + ni * 16 + l15;
        b[ni] = *(const bf16x8*)&Bs[row * 64 + (((ks << 2) | quad) ^ (row & 7)) * 8];
      }
      #pragma unroll
      for (int mi = 0; mi < 4; ++mi)
        #pragma unroll
        for (int ni = 0; ni < 4; ++ni)
          acc[mi][ni] = __builtin_amdgcn_mfma_f32_16x16x32_bf16(a[mi], b[ni], acc[mi][ni], 0, 0, 0);
    }
  }

  if (z < 2) {
    __bf16* out = (z == 0) ? Qb : Kb;
    const float sc = (z == 0) ? QSCALE : 1.0f;
    #pragma unroll
    for (int mi = 0; mi < 4; ++mi) {
      const int row0 = rowBase + wm * 64 + mi * 16 + quad * 4;
      #pragma unroll
      for (int ni = 0; ni < 4; ++ni) {
        const int col = colBase + wn * 64 + ni * 16 + l15;
        #pragma unroll
        for (int r = 0; r < 4; ++r)
          out[(size_t)(row0 + r) * DIM + col] = (__bf16)(acc[mi][ni][r] * sc);
      }
    }
    return;
  }

  // z == 2: transpose epilogue (verified R8). Ts element (d,k) at
  // d*128 + ((k>>3)^(d&7))*8 + (k&7); rows=keys, cols=d. Uses first 32 KB.
  __syncthreads();
  __bf16* Ts = &S[0][0][0];           // 128x128 bf16 = 32 KB
  #pragma unroll
  for (int mi = 0; mi < 4; ++mi) {
    const int bk3 = wm * 8 + mi * 2 + (quad >> 1);   // key_local >> 3
    #pragma unroll
    for (int ni = 0; ni < 4; ++ni) {
      const int dl = wn * 64 + ni * 16 + l15;        // d_local
      bf16x4 pk;
      #pragma unroll
      for (int r = 0; r < 4; ++r) pk[r] = (__bf16)acc[mi][ni][r];
      *(bf16x4*)&Ts[dl * 128 + (bk3 ^ (dl & 7)) * 8 + (quad & 1) * 4] = pk;
    }
  }
  __syncthreads();
  const int d = t >> 1, khh = t & 1;
  const size_t vrow = (size_t)((rowBase >> 11) * HEADS * HDIM) + colBase + d;
  const int key0g = rowBase & (SEQ - 1);
  #pragma unroll
  for (int j = 0; j < 8; ++j) {
    const int kc = khh * 8 + j;
    const int lc = (kc & 8) | ((kc ^ d) & 7);
    const bf16x8 v = *(const bf16x8*)&Ts[d * 128 + lc * 8];
    *(bf16x8*)&VT[vrow * SEQ + key0g + kc * 8] = v;
  }
}

// ---------------------------------------------------------------------------
// Flash attention v7c: full-rate 32x32x16 MFMA everywhere.
// Block = 4 waves, each wave owns 32 q-rows x ALL keys (no kh split, no
// cross-wave merge). Swapped QK^T (mfma(K,Q)) puts P row=key, col=q; P is
// packed to bf16 and redistributed with permlane32_swap into the A-frags of
// full-rate 32x32x16 PV MFMAs (T12). Row sums on the VALU accumulate the
// BF16-ROUNDED p (recovered from the packed word) so numerator and
// denominator share rounding (v6-proven semantics). Double-buffered K/V
// staging; EXPLICIT vmcnt(0) drain before the barrier closes the
// global_load_lds visibility race (v7/v7b intermittent divergence).
// ---------------------------------------------------------------------------
__global__ __launch_bounds__(256, 2) void attn_kernel(
    const __bf16* __restrict__ Qb, const __bf16* __restrict__ Kb,
    const __bf16* __restrict__ VT, __bf16* __restrict__ Ob) {
  __shared__ __bf16 KV[2][2][64 * 64];   // [buf][K|V][64x64], XOR-swizzled rows

  const int t = threadIdx.x, lane = t & 63, wave = t >> 6;
  const int x = lane & 31, hi = lane >> 5;
  const int bh = blockIdx.y, b = bh >> 4, h = bh & 15;
  const int qbase = blockIdx.x * 128 + wave * 32;
  const int srow = lane >> 3;
  const int scol = ((lane & 7) ^ srow) * 8;

  const __bf16* Kbh = Kb + (size_t)b * SEQ * DIM + h * HDIM;
  const __bf16* Vbh = VT + (size_t)bh * HDIM * SEQ;

  // Q B-frags: col = x = q_local, k = kd*16 + hi*8 + j  (Q pre-scaled by QSCALE)
  bf16x8 qf[4];
  #pragma unroll
  for (int kd = 0; kd < 4; ++kd)
    qf[kd] = *(const bf16x8*)&Qb[(size_t)(b * SEQ + qbase + x) * DIM
                                 + h * HDIM + kd * 16 + hi * 8];

  f32x16 o0 = {}, o1 = {};   // o[dblock]: row=q=crow(r,hi), col=d=dblock*32+x
  float lsum = 0.f;          // per-lane partial rowsum for q=x (own hi-half keys)

  const int he16 = (hi ^ (x & 7)) << 4;  // swizzle slot byte base
  const int rowb = x * 128;              // LDS row byte offset (key row / d row)

  auto stage = [&](int jb, int buf) {
    #pragma unroll
    for (int i = 0; i < 2; ++i) {
      const int c = wave * 2 + i;
      const int row = c * 8 + srow;
      glds16(&Kbh[(size_t)(jb + row) * DIM + scol], &KV[buf][0][c * 512]);
      glds16(&Vbh[(size_t)row * SEQ + jb + scol], &KV[buf][1][c * 512]);
    }
  };

  stage(0, 0);
  for (int j = 0; j < SEQ / 64; ++j) {
    const int buf = j & 1;
    wait_dma0();               // guarantee this wave's DMAs landed in LDS
    __syncthreads();           // ...before any wave reads the staged tile
    if (j + 1 < SEQ / 64) stage((j + 1) * 64, buf ^ 1);
    const char* Ks = (const char*)KV[buf][0];
    const char* Vs = (const char*)KV[buf][1];

    // QK^T, both 32-key subtiles: sT col=q(x), row=key=crow(r,hi)
    f32x16 sT0 = {}, sT1 = {};
    #pragma unroll
    for (int kd = 0; kd < 4; ++kd) {
      const bf16x8 kf = *(const bf16x8*)(Ks + rowb + (he16 ^ (kd << 5)));
      sT0 = __builtin_amdgcn_mfma_f32_32x32x16_bf16(kf, qf[kd], sT0, 0, 0, 0);
    }
    #pragma unroll
    for (int kd = 0; kd < 4; ++kd) {
      const bf16x8 kf = *(const bf16x8*)(Ks + 4096 + rowb + (he16 ^ (kd << 5)));
      sT1 = __builtin_amdgcn_mfma_f32_32x32x16_bf16(kf, qf[kd], sT1, 0, 0, 0);
    }

    // per subtile: exp2 -> pack -> permlane swap -> PV (kt=1 pack overlaps kt=0 PV)
    #pragma unroll
    for (int kt = 0; kt < 2; ++kt) {
      const f32x16 s = kt ? sT1 : sT0;
      unsigned w[8];
      #pragma unroll
      for (int i = 0; i < 8; ++i) {
        const float p0 = __builtin_amdgcn_exp2f(s[2 * i]);
        const float p1 = __builtin_amdgcn_exp2f(s[2 * i + 1]);
        bf16x2 pk; pk[0] = (__bf16)p0; pk[1] = (__bf16)p1;
        const unsigned u = __builtin_bit_cast(unsigned, pk);
        w[i] = u;
        // denominator sums the BF16-ROUNDED p (matches the PV numerator's
        // rounding; bf16->f32 is just a shift / mask on the packed word)
        lsum += __builtin_bit_cast(float, u << 16)
              + __builtin_bit_cast(float, u & 0xffff0000u);
      }
      // F0 = keys [kt*32, kt*32+16): dwords {w0,w1,partner w0,w1} per hi-half
      // F1 = keys [kt*32+16, kt*32+32)
#if __has_builtin(__builtin_amdgcn_permlane32_swap)
      const auto s02 = __builtin_amdgcn_permlane32_swap(w[0], w[2], false, false);
      const auto s13 = __builtin_amdgcn_permlane32_swap(w[1], w[3], false, false);
      const auto s46 = __builtin_amdgcn_permlane32_swap(w[4], w[6], false, false);
      const auto s57 = __builtin_amdgcn_permlane32_swap(w[5], w[7], false, false);
      const u32x4v f0v = {(unsigned)s02[0], (unsigned)s13[0], (unsigned)s02[1], (unsigned)s13[1]};
      const u32x4v f1v = {(unsigned)s46[0], (unsigned)s57[0], (unsigned)s46[1], (unsigned)s57[1]};
#else
      const unsigned q0 = __shfl_xor((int)w[0], 32, 64), q1 = __shfl_xor((int)w[1], 32, 64);
      const unsigned q2 = __shfl_xor((int)w[2], 32, 64), q3 = __shfl_xor((int)w[3], 32, 64);
      const unsigned q4 = __shfl_xor((int)w[4], 32, 64), q5 = __shfl_xor((int)w[5], 32, 64);
      const unsigned q6 = __shfl_xor((int)w[6], 32, 64), q7 = __shfl_xor((int)w[7], 32, 64);
      const u32x4v f0v = {hi ? q2 : w[0], hi ? q3 : w[1], hi ? w[2] : q0, hi ? w[3] : q1};
      const u32x4v f1v = {hi ? q6 : w[4], hi ? q7 : w[5], hi ? w[6] : q4, hi ? w[7] : q5};
#endif
      const bf16x8 F0 = __builtin_bit_cast(bf16x8, f0v);
      const bf16x8 F1 = __builtin_bit_cast(bf16x8, f1v);

      // PV: V B-frag col=d (=dblock*32+x), k=hi*8+j keys; slot group
      // (kt*4 + kfr*2 + hi) ^ (d&7) -> byte he16 ^ (kt<<6) ^ (kfr<<5)
      const int kb0 = kt << 6;
      {
        const bf16x8 va = *(const bf16x8*)(Vs + rowb + (he16 ^ kb0));
        const bf16x8 vb = *(const bf16x8*)(Vs + 4096 + rowb + (he16 ^ kb0));
        o0 = __builtin_amdgcn_mfma_f32_32x32x16_bf16(F0, va, o0, 0, 0, 0);
        o1 = __builtin_amdgcn_mfma_f32_32x32x16_bf16(F0, vb, o1, 0, 0, 0);
      }
      {
        const bf16x8 va = *(const bf16x8*)(Vs + rowb + (he16 ^ (kb0 | 32)));
        const bf16x8 vb = *(const bf16x8*)(Vs + 4096 + rowb + (he16 ^ (kb0 | 32)));
        o0 = __builtin_amdgcn_mfma_f32_32x32x16_bf16(F1, va, o0, 0, 0, 0);
        o1 = __builtin_amdgcn_mfma_f32_32x32x16_bf16(F1, vb, o1, 0, 0, 0);
      }
    }
  }

  // finish: l[q=x] = own-half sum + partner-half sum; normalize + write.
  const float ltot = lsum + __shfl_xor(lsum, 32, 64);
  const float linv = 1.f / ltot;
  #pragma unroll
  for (int r = 0; r < 16; ++r) {
    const int q = (r & 3) + 8 * (r >> 2) + 4 * hi;
    const float inv = __shfl(linv, q, 64);   // linv lives at lane q (both halves)
    __bf16* dst = &Ob[(size_t)(b * SEQ + qbase + q) * DIM + h * HDIM + x];
    dst[0]  = (__bf16)(o0[r] * inv);
    dst[32] = (__bf16)(o1[r] * inv);
  }
}

// ---------------------------------------------------------------------------
// Output projection v2: 64x128 tile, double-buffered stage-ahead K-loop +
// XCD swizzle (512 = 8 x 64). fp32 out + bias.
// ---------------------------------------------------------------------------
__global__ __launch_bounds__(256, 2) void outproj_kernel(
    const __bf16* __restrict__ A, const __bf16* __restrict__ Bt,
    const float* __restrict__ bias, float* __restrict__ out) {
  const int lin = blockIdx.x + 8 * blockIdx.y;
  const int swz = (lin & 7) * 64 + (lin >> 3);       // 64 roles per XCD
  const int bx = swz & 7, by = swz >> 3;

  __shared__ __bf16 S[2][12288];      // per buf: A 64x64 (4096) + B 128x64 (8192)

  const int t = threadIdx.x, lane = t & 63, wave = t >> 6;
  const int l15 = lane & 15, quad = lane >> 4;
  const int wm = wave & 1, wn = wave >> 1;
  const int rowBase = by * 64, colBase = bx * 128;
  const int srow = lane >> 3;
  const int scol = ((lane & 7) ^ srow) * 8;

  f32x4 acc[2][4] = {};

  auto stage = [&](int kb, int buf) {
    #pragma unroll
    for (int i = 0; i < 2; ++i) {
      const int c = wave * 2 + i;
      const int row = c * 8 + srow;
      glds16(&A[(size_t)(rowBase + row) * DIM + kb + scol], &S[buf][c * 512]);
    }
    #pragma unroll
    for (int i = 0; i < 4; ++i) {
      const int c = wave * 4 + i;
      const int row = c * 8 + srow;
      glds16(&Bt[(size_t)(colBase + row) * DIM + kb + scol], &S[buf][4096 + c * 512]);
    }
  };

  stage(0, 0);
  for (int kb = 0; kb < DIM / 64; ++kb) {
    const int buf = kb & 1;
    wait_dma0();
    __syncthreads();
    if (kb + 1 < DIM / 64) stage((kb + 1) * 64, buf ^ 1);
    const __bf16* As = &S[buf][0];
    const __bf16* Bs = &S[buf][4096];
    #pragma unroll
    for (int ks = 0; ks < 2; ++ks) {
      bf16x8 a[2], b[4];
      #pragma unroll
      for (int mi = 0; mi < 2; ++mi) {
        const int row = wm * 32 + mi * 16 + l15;
        a[mi] = *(const bf16x8*)&As[row * 64 + (((ks << 2) | quad) ^ (row & 7)) * 8];
      }
      #pragma unroll
      for (int ni = 0; ni < 4; ++ni) {
        const int row = wn * 64 + ni * 16 + l15;
        b[ni] = *(const bf16x8*)&Bs[row * 64 + (((ks << 2) | quad) ^ (row & 7)) * 8];
      }
      #pragma unroll
      for (int mi = 0; mi < 2; ++mi)
        #pragma unroll
        for (int ni = 0; ni < 4; ++ni)
          acc[mi][ni] = __builtin_amdgcn_mfma_f32_16x16x32_bf16(a[mi], b[ni], acc[mi][ni], 0, 0, 0);
    }
  }

  #pragma unroll
  for (int mi = 0; mi < 2; ++mi) {
    const int row0 = rowBase + wm * 32 + mi * 16 + quad * 4;
    #pragma unroll
    for (int ni = 0; ni < 4; ++ni) {
      const int col = colBase + wn * 64 + ni * 16 + l15;
      const float bb = bias[col];
      #pragma unroll
      for (int r = 0; r < 4; ++r)
        out[(size_t)(row0 + r) * DIM + col] = acc[mi][ni][r] + bb;
    }
  }
}

// ---------------------------------------------------------------------------
// ws layout (bf16, NEL = 4194304): xb yb Wt[4M] Qb Kb VT = 50.3 MB.
// Ob aliases xb (dead after projections).
// ---------------------------------------------------------------------------
extern "C" void kernel_launch(void* const* d_in, const int* in_sizes, int n_in,
                              void* d_out, int out_size, void* d_ws, size_t ws_size,
                              hipStream_t stream) {
  const float* x  = (const float*)d_in[0];
  const float* y  = (const float*)d_in[1];
  const float* Wq = (const float*)d_in[2];
  const float* Wk = (const float*)d_in[3];
  const float* Wv = (const float*)d_in[4];
  const float* Wp = (const float*)d_in[5];
  const float* bp = (const float*)d_in[6];
  float* out = (float*)d_out;

  const size_t NEL = (size_t)ROWS * DIM;
  __bf16* xb = (__bf16*)d_ws;
  __bf16* yb = xb + NEL;
  __bf16* Wt = yb + NEL;            // [4][1024][1024] (q,k,v,p), transposed [n][k]
  __bf16* Qb = Wt + NEL;
  __bf16* Kb = Qb + NEL;
  __bf16* VT = Kb + NEL;
  __bf16* Ob = xb;                  // alias: xb dead after projections

  prep_kernel<<<dim3(1024, 1, 9), 256, 0, stream>>>(x, y, Wq, Wk, Wv, Wp, xb, yb, Wt);
  proj_kernel<<<dim3(DIM / 128, ROWS / 128, 3), 256, 0, stream>>>(xb, yb, Wt, Qb, Kb, VT);
  attn_kernel<<<dim3(SEQ / 128, BATCH * HEADS), 256, 0, stream>>>(Qb, Kb, VT, Ob);
  outproj_kernel<<<dim3(DIM / 128, ROWS / 64), 256, 0, stream>>>(Ob, Wt + 3 * NEL / 4, bp, out);
}

// Round 7
// 186.901 us; speedup vs baseline: 1.1533x; 1.0025x over previous
//
#include <hip/hip_runtime.h>
#include <hip/hip_bf16.h>
#include <cstdint>

#define DIM   1024
#define HEADS 16
#define HDIM  64
#define BATCH 2
#define SEQ   2048
#define ROWS  (BATCH*SEQ)   // 4096
static constexpr float QSCALE = 0.18033688f;        // HDIM^-0.5 * log2(e)

typedef float  f32x4  __attribute__((ext_vector_type(4)));
typedef float  f32x16 __attribute__((ext_vector_type(16)));
typedef float  float4v __attribute__((ext_vector_type(4)));
typedef __bf16 bf16x8 __attribute__((ext_vector_type(8)));
typedef __bf16 bf16x4 __attribute__((ext_vector_type(4)));
typedef __bf16 bf16x2 __attribute__((ext_vector_type(2)));
typedef unsigned u32x4v __attribute__((ext_vector_type(4)));

// async global->LDS, 16B per lane; LDS dest is wave-uniform base + lane*16B
__device__ __forceinline__ void glds16(const __bf16* g, __bf16* l) {
  __builtin_amdgcn_global_load_lds(
      (const __attribute__((address_space(1))) void*)g,
      (__attribute__((address_space(3))) void*)l, 16, 0, 0);
}

// Explicit drain of async global->LDS DMAs before publishing via barrier.
__device__ __forceinline__ void wait_dma0() {
  asm volatile("s_waitcnt vmcnt(0) lgkmcnt(0)" ::: "memory");
}

// ---------------------------------------------------------------------------
// prep: z 0..7 -> fp32->bf16 convert of [x|y]; z == 8 -> W -> Wt[n][k] bf16.
// ---------------------------------------------------------------------------
__global__ __launch_bounds__(256) void prep_kernel(
    const float* __restrict__ x, const float* __restrict__ y,
    const float* __restrict__ Wq, const float* __restrict__ Wk,
    const float* __restrict__ Wv, const float* __restrict__ Wp,
    __bf16* __restrict__ xb, __bf16* __restrict__ yb, __bf16* __restrict__ Wt) {
  const int z = blockIdx.z, t = threadIdx.x;
  const size_t NEL = (size_t)ROWS * DIM;
  if (z < 8) {
    size_t idx = (((size_t)z * 1024 + blockIdx.x) * 256 + t) * 4;
    const float* s; __bf16* d;
    if (idx < NEL) { s = x + idx; d = xb + idx; }
    else           { s = y + (idx - NEL); d = yb + (idx - NEL); }
    const float4v v = *(const float4v*)s;
    bf16x4 o;
    o[0] = (__bf16)v[0]; o[1] = (__bf16)v[1]; o[2] = (__bf16)v[2]; o[3] = (__bf16)v[3];
    *(bf16x4*)d = o;
    return;
  }
  const int w = blockIdx.x >> 8, rem = blockIdx.x & 255;
  const float* W = (w == 0) ? Wq : (w == 1) ? Wk : (w == 2) ? Wv : Wp;
  __bf16* dst = Wt + (size_t)w * DIM * DIM;
  const int n0 = (rem & 15) * 64, k0 = (rem >> 4) * 64;
  __shared__ float T[64][65];
  const int col = t & 63, rw = t >> 6;
  #pragma unroll
  for (int p = 0; p < 16; ++p) {
    const int row = p * 4 + rw;
    T[row][col] = W[(size_t)(k0 + row) * DIM + n0 + col];
  }
  __syncthreads();
  #pragma unroll
  for (int p = 0; p < 16; ++p) {
    const int row = p * 4 + rw;
    dst[(size_t)(n0 + row) * DIM + k0 + col] = (__bf16)T[col][row];
  }
}

// ---------------------------------------------------------------------------
// Fused QKV projection v2: double-buffered stage-ahead K-loop (one barrier
// per K-step, DMAs for tile j+1 in flight during compute of tile j) + XCD-
// aware bijective block swizzle (768 = 8 x 96) so blocks sharing an A panel
// share one XCD's L2.
// z: 0 -> Q = xb@Wq^T * QSCALE, 1 -> K = yb@Wk^T, 2 -> V = yb@Wv^T written
// TRANSPOSED to VT[(b*16+h)*64+d][key] via swizzled in-LDS transpose.
// ---------------------------------------------------------------------------
__global__ __launch_bounds__(256, 2) void proj_kernel(
    const __bf16* __restrict__ xb, const __bf16* __restrict__ yb,
    const __bf16* __restrict__ Wt,
    __bf16* __restrict__ Qb, __bf16* __restrict__ Kb, __bf16* __restrict__ VT) {
  // bijective XCD swizzle: linear id in dispatch order (x fastest) -> role id
  const int lin = blockIdx.x + 8 * (blockIdx.y + 32 * blockIdx.z);
  const int swz = (lin & 7) * 96 + (lin >> 3);       // 96 roles per XCD
  const int bx = swz & 7, by = (swz >> 3) & 31, z = swz >> 8;

  const __bf16* A = (z == 0) ? xb : yb;
  const __bf16* Bt = Wt + (size_t)z * DIM * DIM;

  __shared__ __bf16 S[2][2][128 * 64];   // [buf][A|B]; 64 KB

  const int t = threadIdx.x, lane = t & 63, wave = t >> 6;
  const int l15 = lane & 15, quad = lane >> 4;
  const int wm = wave & 1, wn = wave >> 1;
  const int rowBase = by * 128, colBase = bx * 128;
  const int srow = lane >> 3;
  const int scol = ((lane & 7) ^ srow) * 8;

  f32x4 acc[4][4] = {};

  auto stage = [&](int kb, int buf) {
    #pragma unroll
    for (int i = 0; i < 4; ++i) {
      const int c = wave * 4 + i;
      const int row = c * 8 + srow;
      glds16(&A[(size_t)(rowBase + row) * DIM + kb + scol], &S[buf][0][c * 512]);
      glds16(&Bt[(size_t)(colBase + row) * DIM + kb + scol], &S[buf][1][c * 512]);
    }
  };

  stage(0, 0);
  for (int j = 0; j < DIM / 64; ++j) {
    const int buf = j & 1;
    wait_dma0();               // stage(j) landed (compute of j-1 covered it)
    __syncthreads();           // publish buf; all waves done with buf^1
    if (j + 1 < DIM / 64) stage((j + 1) * 64, buf ^ 1);
    const __bf16* As = S[buf][0];
    const __bf16* Bs = S[buf][1];
    #pragma unroll
    for (int ks = 0; ks < 2; ++ks) {
      bf16x8 a[4], b[4];
      #pragma unroll
      for (int mi = 0; mi < 4; ++mi) {
        const int row = wm * 64 + mi * 16 + l15;
        a[mi] = *(const bf16x8*)&As[row * 64 + (((ks << 2) | quad) ^ (row & 7)) * 8];
      }
      #pragma unroll
      for (int ni = 0; ni < 4; ++ni) {
        const int row = wn * 64 + ni * 16 + l15;
        b[ni] = *(const bf16x8*)&Bs[row * 64 + (((ks << 2) | quad) ^ (row & 7)) * 8];
      }
      #pragma unroll
      for (int mi = 0; mi < 4; ++mi)
        #pragma unroll
        for (int ni = 0; ni < 4; ++ni)
          acc[mi][ni] = __builtin_amdgcn_mfma_f32_16x16x32_bf16(a[mi], b[ni], acc[mi][ni], 0, 0, 0);
    }
  }

  if (z < 2) {
    __bf16* out = (z == 0) ? Qb : Kb;
    const float sc = (z == 0) ? QSCALE : 1.0f;
    #pragma unroll
    for (int mi = 0; mi < 4; ++mi) {
      const int row0 = rowBase + wm * 64 + mi * 16 + quad * 4;
      #pragma unroll
      for (int ni = 0; ni < 4; ++ni) {
        const int col = colBase + wn * 64 + ni * 16 + l15;
        #pragma unroll
        for (int r = 0; r < 4; ++r)
          out[(size_t)(row0 + r) * DIM + col] = (__bf16)(acc[mi][ni][r] * sc);
      }
    }
    return;
  }

  // z == 2: transpose epilogue (verified R8). Ts element (d,k) at
  // d*128 + ((k>>3)^(d&7))*8 + (k&7); rows=keys, cols=d. Uses first 32 KB.
  __syncthreads();
  __bf16* Ts = &S[0][0][0];           // 128x128 bf16 = 32 KB
  #pragma unroll
  for (int mi = 0; mi < 4; ++mi) {
    const int bk3 = wm * 8 + mi * 2 + (quad >> 1);   // key_local >> 3
    #pragma unroll
    for (int ni = 0; ni < 4; ++ni) {
      const int dl = wn * 64 + ni * 16 + l15;        // d_local
      bf16x4 pk;
      #pragma unroll
      for (int r = 0; r < 4; ++r) pk[r] = (__bf16)acc[mi][ni][r];
      *(bf16x4*)&Ts[dl * 128 + (bk3 ^ (dl & 7)) * 8 + (quad & 1) * 4] = pk;
    }
  }
  __syncthreads();
  const int d = t >> 1, khh = t & 1;
  const size_t vrow = (size_t)((rowBase >> 11) * HEADS * HDIM) + colBase + d;
  const int key0g = rowBase & (SEQ - 1);
  #pragma unroll
  for (int j = 0; j < 8; ++j) {
    const int kc = khh * 8 + j;
    const int lc = (kc & 8) | ((kc ^ d) & 7);
    const bf16x8 v = *(const bf16x8*)&Ts[d * 128 + lc * 8];
    *(bf16x8*)&VT[vrow * SEQ + key0g + kc * 8] = v;
  }
}

// ---------------------------------------------------------------------------
// Flash attention v10 (BISECT (b) on R4-passing base): V staged in LDS and
// the whole loop/staging/F-construction byte-identical to R4. ONE change:
// row sums move to ones-MFMA on the F fragments -> lacc rows = q = same
// per-register rows as o (PV A-frag row = q), so normalize is in-lane
// (inv = 1/lacc[r], no shuffles). Denominator = sum of bf16-rounded p (the
// same F the numerator uses) -> v6-proven rounding cancellation.
// [R5/R6 lesson: V-direct-to-register + unroll-2 loop fails deterministically
// (absmax 0.255, bit-identical across variants) -> abandoned.]
// ---------------------------------------------------------------------------
__global__ __launch_bounds__(256, 2) void attn_kernel(
    const __bf16* __restrict__ Qb, const __bf16* __restrict__ Kb,
    const __bf16* __restrict__ VT, __bf16* __restrict__ Ob) {
  __shared__ __bf16 KV[2][2][64 * 64];   // [buf][K|V][64x64], XOR-swizzled rows

  const int t = threadIdx.x, lane = t & 63, wave = t >> 6;
  const int x = lane & 31, hi = lane >> 5;
  const int bh = blockIdx.y, b = bh >> 4, h = bh & 15;
  const int qbase = blockIdx.x * 128 + wave * 32;
  const int srow = lane >> 3;
  const int scol = ((lane & 7) ^ srow) * 8;

  const __bf16* Kbh = Kb + (size_t)b * SEQ * DIM + h * HDIM;
  const __bf16* Vbh = VT + (size_t)bh * HDIM * SEQ;

  // Q B-frags: col = x = q_local, k = kd*16 + hi*8 + j  (Q pre-scaled by QSCALE)
  bf16x8 qf[4];
  #pragma unroll
  for (int kd = 0; kd < 4; ++kd)
    qf[kd] = *(const bf16x8*)&Qb[(size_t)(b * SEQ + qbase + x) * DIM
                                 + h * HDIM + kd * 16 + hi * 8];

  f32x16 o0 = {}, o1 = {};   // o[dblock]: row=q=crow(r,hi), col=d=dblock*32+x
  f32x16 lacc = {};          // row sums via ones-MFMA: row=q=crow(r,hi)

  bf16x8 ones8;
  #pragma unroll
  for (int i = 0; i < 8; ++i) ones8[i] = (__bf16)1.0f;

  const int he16 = (hi ^ (x & 7)) << 4;  // swizzle slot byte base
  const int rowb = x * 128;              // LDS row byte offset (key row / d row)

  auto stage = [&](int jb, int buf) {
    #pragma unroll
    for (int i = 0; i < 2; ++i) {
      const int c = wave * 2 + i;
      const int row = c * 8 + srow;
      glds16(&Kbh[(size_t)(jb + row) * DIM + scol], &KV[buf][0][c * 512]);
      glds16(&Vbh[(size_t)row * SEQ + jb + scol], &KV[buf][1][c * 512]);
    }
  };

  stage(0, 0);
  for (int j = 0; j < SEQ / 64; ++j) {
    const int buf = j & 1;
    wait_dma0();               // guarantee this wave's DMAs landed in LDS
    __syncthreads();           // ...before any wave reads the staged tile
    if (j + 1 < SEQ / 64) stage((j + 1) * 64, buf ^ 1);
    const char* Ks = (const char*)KV[buf][0];
    const char* Vs = (const char*)KV[buf][1];

    // QK^T, both 32-key subtiles: sT col=q(x), row=key=crow(r,hi)
    f32x16 sT0 = {}, sT1 = {};
    #pragma unroll
    for (int kd = 0; kd < 4; ++kd) {
      const bf16x8 kf = *(const bf16x8*)(Ks + rowb + (he16 ^ (kd << 5)));
      sT0 = __builtin_amdgcn_mfma_f32_32x32x16_bf16(kf, qf[kd], sT0, 0, 0, 0);
    }
    #pragma unroll
    for (int kd = 0; kd < 4; ++kd) {
      const bf16x8 kf = *(const bf16x8*)(Ks + 4096 + rowb + (he16 ^ (kd << 5)));
      sT1 = __builtin_amdgcn_mfma_f32_32x32x16_bf16(kf, qf[kd], sT1, 0, 0, 0);
    }

    // per subtile: exp2 -> pack -> permlane swap -> rowsum-MFMA + PV
    #pragma unroll
    for (int kt = 0; kt < 2; ++kt) {
      const f32x16 s = kt ? sT1 : sT0;
      unsigned w[8];
      #pragma unroll
      for (int i = 0; i < 8; ++i) {
        const float p0 = __builtin_amdgcn_exp2f(s[2 * i]);
        const float p1 = __builtin_amdgcn_exp2f(s[2 * i + 1]);
        bf16x2 pk; pk[0] = (__bf16)p0; pk[1] = (__bf16)p1;
        w[i] = __builtin_bit_cast(unsigned, pk);
      }
      // F0 = keys [kt*32, kt*32+16): dwords {w0,w1,partner w0,w1} per hi-half
      // F1 = keys [kt*32+16, kt*32+32)
#if __has_builtin(__builtin_amdgcn_permlane32_swap)
      const auto s02 = __builtin_amdgcn_permlane32_swap(w[0], w[2], false, false);
      const auto s13 = __builtin_amdgcn_permlane32_swap(w[1], w[3], false, false);
      const auto s46 = __builtin_amdgcn_permlane32_swap(w[4], w[6], false, false);
      const auto s57 = __builtin_amdgcn_permlane32_swap(w[5], w[7], false, false);
      const u32x4v f0v = {(unsigned)s02[0], (unsigned)s13[0], (unsigned)s02[1], (unsigned)s13[1]};
      const u32x4v f1v = {(unsigned)s46[0], (unsigned)s57[0], (unsigned)s46[1], (unsigned)s57[1]};
#else
      const unsigned q0 = __shfl_xor((int)w[0], 32, 64), q1 = __shfl_xor((int)w[1], 32, 64);
      const unsigned q2 = __shfl_xor((int)w[2], 32, 64), q3 = __shfl_xor((int)w[3], 32, 64);
      const unsigned q4 = __shfl_xor((int)w[4], 32, 64), q5 = __shfl_xor((int)w[5], 32, 64);
      const unsigned q6 = __shfl_xor((int)w[6], 32, 64), q7 = __shfl_xor((int)w[7], 32, 64);
      const u32x4v f0v = {hi ? q2 : w[0], hi ? q3 : w[1], hi ? w[2] : q0, hi ? w[3] : q1};
      const u32x4v f1v = {hi ? q6 : w[4], hi ? q7 : w[5], hi ? w[6] : q4, hi ? w[7] : q5};
#endif
      const bf16x8 F0 = __builtin_bit_cast(bf16x8, f0v);
      const bf16x8 F1 = __builtin_bit_cast(bf16x8, f1v);

      // row sums on the MFMA pipe: denominator = sum of bf16-rounded p,
      // same F fragments as the PV numerator.
      lacc = __builtin_amdgcn_mfma_f32_32x32x16_bf16(F0, ones8, lacc, 0, 0, 0);
      lacc = __builtin_amdgcn_mfma_f32_32x32x16_bf16(F1, ones8, lacc, 0, 0, 0);

      // PV: V B-frag col=d (=dblock*32+x), k=hi*8+j keys; slot group
      // (kt*4 + kfr*2 + hi) ^ (d&7) -> byte he16 ^ (kt<<6) ^ (kfr<<5)
      const int kb0 = kt << 6;
      {
        const bf16x8 va = *(const bf16x8*)(Vs + rowb + (he16 ^ kb0));
        const bf16x8 vb = *(const bf16x8*)(Vs + 4096 + rowb + (he16 ^ kb0));
        o0 = __builtin_amdgcn_mfma_f32_32x32x16_bf16(F0, va, o0, 0, 0, 0);
        o1 = __builtin_amdgcn_mfma_f32_32x32x16_bf16(F0, vb, o1, 0, 0, 0);
      }
      {
        const bf16x8 va = *(const bf16x8*)(Vs + rowb + (he16 ^ (kb0 | 32)));
        const bf16x8 vb = *(const bf16x8*)(Vs + 4096 + rowb + (he16 ^ (kb0 | 32)));
        o0 = __builtin_amdgcn_mfma_f32_32x32x16_bf16(F1, va, o0, 0, 0, 0);
        o1 = __builtin_amdgcn_mfma_f32_32x32x16_bf16(F1, vb, o1, 0, 0, 0);
      }
    }
  }

  // finish: inv = 1/lacc[r] in-lane (lacc rows match o rows); no shuffles.
  #pragma unroll
  for (int r = 0; r < 16; ++r) {
    const int q = (r & 3) + 8 * (r >> 2) + 4 * hi;
    const float inv = 1.f / lacc[r];
    __bf16* dst = &Ob[(size_t)(b * SEQ + qbase + q) * DIM + h * HDIM + x];
    dst[0]  = (__bf16)(o0[r] * inv);
    dst[32] = (__bf16)(o1[r] * inv);
  }
}

// ---------------------------------------------------------------------------
// Output projection v2: 64x128 tile, double-buffered stage-ahead K-loop +
// XCD swizzle (512 = 8 x 64). fp32 out + bias.
// ---------------------------------------------------------------------------
__global__ __launch_bounds__(256, 2) void outproj_kernel(
    const __bf16* __restrict__ A, const __bf16* __restrict__ Bt,
    const float* __restrict__ bias, float* __restrict__ out) {
  const int lin = blockIdx.x + 8 * blockIdx.y;
  const int swz = (lin & 7) * 64 + (lin >> 3);       // 64 roles per XCD
  const int bx = swz & 7, by = swz >> 3;

  __shared__ __bf16 S[2][12288];      // per buf: A 64x64 (4096) + B 128x64 (8192)

  const int t = threadIdx.x, lane = t & 63, wave = t >> 6;
  const int l15 = lane & 15, quad = lane >> 4;
  const int wm = wave & 1, wn = wave >> 1;
  const int rowBase = by * 64, colBase = bx * 128;
  const int srow = lane >> 3;
  const int scol = ((lane & 7) ^ srow) * 8;

  f32x4 acc[2][4] = {};

  auto stage = [&](int kb, int buf) {
    #pragma unroll
    for (int i = 0; i < 2; ++i) {
      const int c = wave * 2 + i;
      const int row = c * 8 + srow;
      glds16(&A[(size_t)(rowBase + row) * DIM + kb + scol], &S[buf][c * 512]);
    }
    #pragma unroll
    for (int i = 0; i < 4; ++i) {
      const int c = wave * 4 + i;
      const int row = c * 8 + srow;
      glds16(&Bt[(size_t)(colBase + row) * DIM + kb + scol], &S[buf][4096 + c * 512]);
    }
  };

  stage(0, 0);
  for (int kb = 0; kb < DIM / 64; ++kb) {
    const int buf = kb & 1;
    wait_dma0();
    __syncthreads();
    if (kb + 1 < DIM / 64) stage((kb + 1) * 64, buf ^ 1);
    const __bf16* As = &S[buf][0];
    const __bf16* Bs = &S[buf][4096];
    #pragma unroll
    for (int ks = 0; ks < 2; ++ks) {
      bf16x8 a[2], b[4];
      #pragma unroll
      for (int mi = 0; mi < 2; ++mi) {
        const int row = wm * 32 + mi * 16 + l15;
        a[mi] = *(const bf16x8*)&As[row * 64 + (((ks << 2) | quad) ^ (row & 7)) * 8];
      }
      #pragma unroll
      for (int ni = 0; ni < 4; ++ni) {
        const int row = wn * 64 + ni * 16 + l15;
        b[ni] = *(const bf16x8*)&Bs[row * 64 + (((ks << 2) | quad) ^ (row & 7)) * 8];
      }
      #pragma unroll
      for (int mi = 0; mi < 2; ++mi)
        #pragma unroll
        for (int ni = 0; ni < 4; ++ni)
          acc[mi][ni] = __builtin_amdgcn_mfma_f32_16x16x32_bf16(a[mi], b[ni], acc[mi][ni], 0, 0, 0);
    }
  }

  #pragma unroll
  for (int mi = 0; mi < 2; ++mi) {
    const int row0 = rowBase + wm * 32 + mi * 16 + quad * 4;
    #pragma unroll
    for (int ni = 0; ni < 4; ++ni) {
      const int col = colBase + wn * 64 + ni * 16 + l15;
      const float bb = bias[col];
      #pragma unroll
      for (int r = 0; r < 4; ++r)
        out[(size_t)(row0 + r) * DIM + col] = acc[mi][ni][r] + bb;
    }
  }
}

// ---------------------------------------------------------------------------
// ws layout (bf16, NEL = 4194304): xb yb Wt[4M] Qb Kb VT = 50.3 MB.
// Ob aliases xb (dead after projections).
// ---------------------------------------------------------------------------
extern "C" void kernel_launch(void* const* d_in, const int* in_sizes, int n_in,
                              void* d_out, int out_size, void* d_ws, size_t ws_size,
                              hipStream_t stream) {
  const float* x  = (const float*)d_in[0];
  const float* y  = (const float*)d_in[1];
  const float* Wq = (const float*)d_in[2];
  const float* Wk = (const float*)d_in[3];
  const float* Wv = (const float*)d_in[4];
  const float* Wp = (const float*)d_in[5];
  const float* bp = (const float*)d_in[6];
  float* out = (float*)d_out;

  const size_t NEL = (size_t)ROWS * DIM;
  __bf16* xb = (__bf16*)d_ws;
  __bf16* yb = xb + NEL;
  __bf16* Wt = yb + NEL;            // [4][1024][1024] (q,k,v,p), transposed [n][k]
  __bf16* Qb = Wt + NEL;
  __bf16* Kb = Qb + NEL;
  __bf16* VT = Kb + NEL;
  __bf16* Ob = xb;                  // alias: xb dead after projections

  prep_kernel<<<dim3(1024, 1, 9), 256, 0, stream>>>(x, y, Wq, Wk, Wv, Wp, xb, yb, Wt);
  proj_kernel<<<dim3(DIM / 128, ROWS / 128, 3), 256, 0, stream>>>(xb, yb, Wt, Qb, Kb, VT);
  attn_kernel<<<dim3(SEQ / 128, BATCH * HEADS), 256, 0, stream>>>(Qb, Kb, VT, Ob);
  outproj_kernel<<<dim3(DIM / 128, ROWS / 64), 256, 0, stream>>>(Ob, Wt + 3 * NEL / 4, bp, out);
}